// Round 7
// baseline (634.205 us; speedup 1.0000x reference)
//
#include <hip/hip_runtime.h>
#include <stdint.h>

// B=8, N=E=2048.  All-fp16 single-product pipeline:
//  1) Xh = fp16(X), Wh = fp16(W)
//  2) Q = Xh·Wh^T + b   -> fp16 Qh
//  3) S = Qh·Xh^T + gamma -> fp16 Sh (+ fused column-softmax partial stats)
//  4) stats combine (8 partials -> Mx, Rs)
//  5) attn[b,m,e] = exp(Sh-M)*R -> fp16 (overlays Qh)
//  6) out = Xh·attn^T -> fp32
//
// R7 vs R6 (627.6 us; GEMM 140 us, MfmaUtil 45%): m201-style phase pipeline.
// Both matrix and LDS pipes were ~45% busy -> barrier-lockstep serialization
// (1 block/CU): after each barrier all waves ds_read THEN MFMA.  Fix: issue
// each phase's ds_reads ONE PHASE EARLY so post-barrier MFMAs start on
// already-landed registers.
//
// Legality (per-wave vmcnt only covers own DMA; collective validity = each
// wave drained own loads + a barrier after):
//   vmcnt deepened 8 -> 4 at EVERY sync, so each half-region is collectively
//   valid ONE SYNC EARLIER than its first read:
//   ledger (steady, outstanding after drain in braces):
//     SYNC1(t): out = {t+1.k0, t+1.k1} -> vmcnt(4) drains t+1.k0 {t+1.k1}
//     SYNC2(t): out = {t+1.k1, t+2.k0} -> vmcnt(4) drains t+1.k1 {t+2.k0}
//   waited loads are ~2 phases (~2600 cyc) old >> L2 latency.
// Read schedule (frag sets aX,aY,aZ / bX,bY; MFMA order UNCHANGED = R2):
//   A: rd aY<-(d,k0,mh1)       ; STG A(e,k1,t+1); MM(mh0, aX,bX)
//   B: rd aZ<-(d,k1,mh0), bY<-(d,k1); STG B(e,k1,t+1); MM(mh1, aY,bX)
//      [(d,k1)=t.k1 collectively valid since SYNC2(t-1) -- drained there]
//   SYNC1 vmcnt(4)
//   C: rd aY<-(d,k1,mh1)       ; STG A(d,k0,t+2); MM(mh0, aZ,bY)
//   D: rd aX<-(e,k0,mh0), bX<-(e,k0); STG B(d,k0,t+2); MM(mh1, aY,bY)
//      [(e,k0)=t+1.k0 valid since SYNC1(t) -- drained there]
//   SYNC2 vmcnt(4)
// W-after-R: every prefetched read retires at the lgkmcnt(0) of the sync
// BEFORE any wave can pass the barrier that precedes the overwriting STG:
//   aY@A reads (d,*,k0), overwritten at C/D after SYNC1 (lgkm0) OK
//   aZ,bY@B read (d,*,k1), overwritten at t+1 A/B after SYNC2 (lgkm0) OK
//   aX,bX@D read (e,*,k0), overwritten at t+1 C/D after SYNC1(t+1) OK
// Prologue: 12 loads, vmcnt(4) drains t0.k0+t0.k1, barrier -> both t0 halves
// collectively valid before any read.  Tails: NT-2 SYNC(4)/SYNC(0); NT-1
// SYNC(0) mid-tile, no trailing sync (epilogue re-syncs).
// absmax MUST equal R6's 0.1679688 exactly (bit-identical arithmetic);
// any drift => race => revert to R6 skeleton.
//
// XCD swizzle (R6, confirmed: FETCH 270->98 MB): each XCD owns a 4(tn)x2(tm)
// sub-grid.  LDS seg-XOR swizzle (0 conflicts) unchanged.

typedef _Float16 f16;
typedef f16 f16x8 __attribute__((ext_vector_type(8)));
typedef f16 f16x4 __attribute__((ext_vector_type(4)));
typedef float f32x4 __attribute__((ext_vector_type(4)));

#define ND 2048
#define NNL 4194304L  // ND*ND
#define NT 32         // K tiles of 64

static __device__ __forceinline__ void stage16(const void* g, void* l) {
  __builtin_amdgcn_global_load_lds(
      (const __attribute__((address_space(1))) uint32_t*)g,
      (__attribute__((address_space(3))) uint32_t*)l, 16, 0, 0);
}

// ---------------- fp32 -> fp16 convert (grid-stride) ----------------
__global__ void cvt_f16(const float* __restrict__ x, f16* __restrict__ h, long n4) {
  const long stride = (long)gridDim.x * 256;
  for (long i = (long)blockIdx.x * 256 + threadIdx.x; i < n4; i += stride) {
    float4 v = reinterpret_cast<const float4*>(x)[i];
    f16x4 o;
    o.x = (f16)v.x; o.y = (f16)v.y; o.z = (f16)v.z; o.w = (f16)v.w;
    reinterpret_cast<f16x4*>(h)[i] = o;
  }
}

// region byte base within smem: d=dbuf(0/1), o=op(0=A,1=B), kh=K-half(0/1)
#define RB(d_, o_, kh_) ((((d_) << 2) | ((o_) << 1) | (kh_)) * 16384)

// stage one 16 KiB half-region (256 rows x 32 f16): 2 x 8 KiB load-rounds.
#define STG(gp_, ro_, t_, kh_)                                           \
  do {                                                                   \
    stage16((gp_) + (long)(t_) * 128 + (kh_) * 64, smem + (ro_) + ld0);  \
    stage16((gp_) + 524288L + (long)(t_) * 128 + (kh_) * 64,             \
            smem + (ro_) + ld1);                                         \
  } while (0)

#define FENCE asm volatile("" ::: "memory")

#define SYNC(vm_)                                                        \
  do {                                                                   \
    asm volatile("s_waitcnt vmcnt(" #vm_ ") lgkmcnt(0)" ::: "memory");   \
    __builtin_amdgcn_s_barrier();                                        \
    FENCE;                                                               \
  } while (0)

// read 4 A-frags for (d,kh,mh) into dst (frag4)
#define RDA(dst_, d_, kh_, mh_)                                          \
  do {                                                                   \
    const char* p_ = smem + RB(d_, 0, kh_) + (mh_) * 4096 + aoff;        \
    (dst_).v[0] = *(const f16x8*)(p_);                                   \
    (dst_).v[1] = *(const f16x8*)(p_ + 1024);                            \
    (dst_).v[2] = *(const f16x8*)(p_ + 2048);                            \
    (dst_).v[3] = *(const f16x8*)(p_ + 3072);                            \
  } while (0)

// read 4 B-frags for (d,kh)
#define RDBF(dst_, d_, kh_)                                              \
  do {                                                                   \
    const char* p_ = smem + RB(d_, 1, kh_) + boff;                       \
    (dst_).v[0] = *(const f16x8*)(p_);                                   \
    (dst_).v[1] = *(const f16x8*)(p_ + 1024);                            \
    (dst_).v[2] = *(const f16x8*)(p_ + 2048);                            \
    (dst_).v[3] = *(const f16x8*)(p_ + 3072);                            \
  } while (0)

// 16 MFMAs: acc[mh*4+mt][nt] += A.v[mt] x B.v[nt]  (order identical to R2)
#define MM(mh_, A_, B_)                                                       \
  do {                                                                        \
    __builtin_amdgcn_s_setprio(1);                                            \
    _Pragma("unroll") for (int mt_ = 0; mt_ < 4; ++mt_) {                     \
      _Pragma("unroll") for (int nt_ = 0; nt_ < 4; ++nt_) {                   \
        acc[(mh_) * 4 + mt_][nt_] = __builtin_amdgcn_mfma_f32_16x16x32_f16(   \
            (A_).v[mt_], (B_).v[nt_], acc[(mh_) * 4 + mt_][nt_], 0, 0, 0);    \
      }                                                                       \
    }                                                                         \
    __builtin_amdgcn_s_setprio(0);                                            \
  } while (0)

struct frag4 { f16x8 v[4]; };

// ---------------- GEMM: C[i,j] = dot(A[i,:], B[j,:])  (row-major, K=2048)
// MODE 1: + bias[j], fp16 store (Ch)
// MODE 0: fp32 store (Cf)
// MODE 2: + gamma, f16 store (Ch) + fused column-softmax partials -> Mp/Sp
template <int MODE>
__launch_bounds__(512, 2) __global__
void gemm256(const f16* __restrict__ A, long sA, const f16* __restrict__ B, long sB,
             const float* __restrict__ bias, const float* __restrict__ gamma,
             float* __restrict__ Cf, f16* __restrict__ Ch,
             float* __restrict__ Mp, float* __restrict__ Sp) {
  __shared__ char smem[131072];

  const int bz = blockIdx.z;
  // XCD-aware remap: xcd = blockIdx.x (= dispatch-linear % 8, x-fastest).
  const int bx = ((blockIdx.x & 1) << 2) | (blockIdx.y & 3);          // tn idx
  const int by = (((blockIdx.x >> 1) & 3) << 1) | (blockIdx.y >> 2);  // tm idx
  const long tm = (long)by * 256;
  const long tn = (long)bx * 256;
  const int tid = threadIdx.x;
  const int lane = tid & 63;
  const int wid = tid >> 6;
  const int wm = (wid >> 2) << 7;  // 0 / 128
  const int wn = (wid & 3) << 6;   // 0 / 64 / 128 / 192

  // staging: fetch global seg s_g = s_lds ^ ((row>>1)&3)
  const int sg = (tid & 3) ^ ((tid >> 3) & 3);
  const char* gA = (const char*)(A + bz * sA + tm * ND) + (long)(tid >> 2) * 4096 + sg * 16;
  const char* gB = (const char*)(B + bz * sB + tn * ND) + (long)(tid >> 2) * 4096 + sg * 16;
  const uint32_t ld0 = tid * 16u;
  const uint32_t ld1 = 8192u + tid * 16u;

  // 16x16x32 frag reader (0 conflicts): LDS seg = (lane>>4) ^ ((row>>1)&3)
  const int segsw = (((lane >> 4) ^ ((lane >> 1) & 3)) << 4);  // bytes
  const int lrow = lane & 15;
  const int aoff = (wm + lrow) * 64 + segsw;
  const int boff = (wn + lrow) * 64 + segsw;

  f32x4 acc[8][4] = {};
  frag4 aX, aY, aZ, bX, bY;

  // prologue: t0.k0, t0.k1, t1.k0 (12 loads); vmcnt(4) drains t0.k0 AND
  // t0.k1 (leaves t1.k0) -> after barrier BOTH t0 halves collectively valid.
  STG(gA, RB(0, 0, 0), 0, 0);
  STG(gB, RB(0, 1, 0), 0, 0);
  STG(gA, RB(0, 0, 1), 0, 1);
  STG(gB, RB(0, 1, 1), 0, 1);
  STG(gA, RB(1, 0, 0), 1, 0);
  STG(gB, RB(1, 1, 0), 1, 0);
  asm volatile("s_waitcnt vmcnt(4)" ::: "memory");
  __builtin_amdgcn_s_barrier();
  FENCE;
  RDA(aX, 0, 0, 0);
  RDBF(bX, 0, 0);

#pragma unroll 2
  for (int t = 0; t < NT - 2; ++t) {
    const int d = t & 1;
    const int e = d ^ 1;
    // A
    RDA(aY, d, 0, 1);
    STG(gA, RB(e, 0, 1), t + 1, 1);
    MM(0, aX, bX);
    // B
    RDA(aZ, d, 1, 0);
    RDBF(bY, d, 1);
    STG(gB, RB(e, 1, 1), t + 1, 1);
    MM(1, aY, bX);
    SYNC(4);  // drains t+1.k0 -> (e,k0) collectively valid for phase D
    // C
    RDA(aY, d, 1, 1);
    STG(gA, RB(d, 0, 0), t + 2, 0);
    MM(0, aZ, bY);
    // D
    RDA(aX, e, 0, 0);
    RDBF(bX, e, 0);
    STG(gB, RB(d, 1, 0), t + 2, 0);
    MM(1, aY, bY);
    SYNC(4);  // drains t+1.k1 -> (e,k1) valid for next tile's phase B
  }
  {  // t = NT-2 (even => d=0, e=1)
    RDA(aY, 0, 0, 1);
    STG(gA, RB(1, 0, 1), NT - 1, 1);
    MM(0, aX, bX);
    RDA(aZ, 0, 1, 0);
    RDBF(bY, 0, 1);
    STG(gB, RB(1, 1, 1), NT - 1, 1);
    MM(1, aY, bX);
    SYNC(4);  // out = {(NT-1).k0, (NT-1).k1} -> drains (NT-1).k0
    RDA(aY, 0, 1, 1);
    MM(0, aZ, bY);
    RDA(aX, 1, 0, 0);
    RDBF(bX, 1, 0);
    MM(1, aY, bY);
    SYNC(0);  // drains (NT-1).k1
  }
  {  // t = NT-1 (odd => d=1)
    RDA(aY, 1, 0, 1);
    MM(0, aX, bX);
    RDA(aZ, 1, 1, 0);
    RDBF(bY, 1, 1);
    MM(1, aY, bX);
    SYNC(0);
    RDA(aY, 1, 1, 1);
    MM(0, aZ, bY);
    MM(1, aY, bY);
    // no sync: epilogue syncs itself where needed
  }

  // epilogue: C/D layout col=lane&15, row=(lane>>4)*4+reg  [verified m89/m91]
  const int rr = (lane >> 4) << 2;
  const int cc = lane & 15;
  const long cb = (long)bz * NNL;
  if constexpr (MODE == 1) {
#pragma unroll
    for (int nt = 0; nt < 4; ++nt) {
      const long col = tn + wn + nt * 16 + cc;
      const float bj = bias[col];
#pragma unroll
      for (int mt = 0; mt < 8; ++mt) {
#pragma unroll
        for (int r = 0; r < 4; ++r) {
          const long row = tm + wm + mt * 16 + rr + r;
          Ch[cb + row * ND + col] = (f16)(acc[mt][nt][r] + bj);
        }
      }
    }
  } else if constexpr (MODE == 0) {
#pragma unroll
    for (int mt = 0; mt < 8; ++mt) {
#pragma unroll
      for (int nt = 0; nt < 4; ++nt) {
#pragma unroll
        for (int r = 0; r < 4; ++r) {
          const long row = tm + wm + mt * 16 + rr + r;
          const long col = tn + wn + nt * 16 + cc;
          Cf[cb + row * ND + col] = acc[mt][nt][r];
        }
      }
    }
  } else {  // MODE 2: f16 score store + fused column-softmax partials
    const float g = gamma[0];
    // round scores to f16 FIRST; all stats from the rounded values so that
    // attn = exact softmax(s16) (dominant-entry rounding cancels).
#pragma unroll
    for (int mt = 0; mt < 8; ++mt)
#pragma unroll
      for (int nt = 0; nt < 4; ++nt)
#pragma unroll
        for (int r = 0; r < 4; ++r)
          acc[mt][nt][r] = (float)(f16)(acc[mt][nt][r] + g);
    __syncthreads();  // all waves done with smem tiles -> safe to reuse
    float* redm = (float*)smem;  // [8 wid][4 nt][16 cc] = 512 floats
    float* reds = redm + 512;
#pragma unroll
    for (int nt = 0; nt < 4; ++nt) {
      float ml = -3.4e38f;
#pragma unroll
      for (int mt = 0; mt < 8; ++mt)
#pragma unroll
        for (int r = 0; r < 4; ++r)
          ml = fmaxf(ml, acc[mt][nt][r]);
      float sl = 0.f;
#pragma unroll
      for (int mt = 0; mt < 8; ++mt)
#pragma unroll
        for (int r = 0; r < 4; ++r)
          sl += __expf(acc[mt][nt][r] - ml);
      // butterfly over lane bits 4,5: combine the 4 rr-stripes of column cc
#pragma unroll
      for (int off = 16; off < 64; off <<= 1) {
        float pm = __shfl_xor(ml, off, 64);
        float ps = __shfl_xor(sl, off, 64);
        float nm = fmaxf(ml, pm);
        sl = sl * __expf(ml - nm) + ps * __expf(pm - nm);
        ml = nm;
      }
      if ((lane >> 4) == 0) {
        redm[wid * 64 + nt * 16 + lrow] = ml;
        reds[wid * 64 + nt * 16 + lrow] = sl;
      }
    }
    __syncthreads();
    if (tid < 256) {
      const float mA = redm[tid], sA = reds[tid];
      const float mB = redm[256 + tid], sB = reds[256 + tid];
      const float m = fmaxf(mA, mB);
      const float s = sA * __expf(mA - m) + sB * __expf(mB - m);
      const long o = ((long)bz * 8 + by) * ND + tn + tid;
      Mp[o] = m;
      Sp[o] = s;
    }
    // S store (f16; acc already rounded so this conversion is exact)
#pragma unroll
    for (int mt = 0; mt < 8; ++mt) {
#pragma unroll
      for (int nt = 0; nt < 4; ++nt) {
#pragma unroll
        for (int r = 0; r < 4; ++r) {
          const long row = tm + wm + mt * 16 + rr + r;
          const long col = tn + wn + nt * 16 + cc;
          Ch[cb + row * ND + col] = (f16)acc[mt][nt][r];
        }
      }
    }
  }
}

// ---------------- stats combine (8 n-segment partials -> Mx, 1/sum) --------
__global__ void stats_combine(const float* __restrict__ Mp, const float* __restrict__ Sp,
                              float* __restrict__ Mx, float* __restrict__ Rs) {
  const int col = blockIdx.x * 256 + threadIdx.x;
  const int b = blockIdx.y;
  float m = -3.4e38f, s = 0.f;
  for (int k = 0; k < 8; ++k) {
    const long o = ((long)b * 8 + k) * ND + col;
    float mk = Mp[o], sk = Sp[o];
    float nm = fmaxf(m, mk);
    s = s * __expf(m - nm) + sk * __expf(mk - nm);
    m = nm;
  }
  Mx[(long)b * ND + col] = m;
  Rs[(long)b * ND + col] = 1.0f / s;
}

// attn[b,m,e] = exp(Sh[b,m,e] - Mx[b,e]) * Rs[b,e]  -> fp16, same layout as Sh
__global__ void scale_exp_kernel(const f16* __restrict__ S, const float* __restrict__ Mx,
                                 const float* __restrict__ Rs, f16* __restrict__ A) {
  const long i8 = (long)blockIdx.x * 256 + threadIdx.x;  // total/8
  const long i = i8 * 8;
  const int b = (int)(i >> 22);     // N*N = 2^22
  const int col = (int)(i & 2047);  // e index (multiple of 8)
  f16x8 s = reinterpret_cast<const f16x8*>(S)[i8];
  const float* mp = &Mx[(long)b * ND + col];
  const float* rp = &Rs[(long)b * ND + col];
  float4 m0 = *reinterpret_cast<const float4*>(mp);
  float4 m1 = *reinterpret_cast<const float4*>(mp + 4);
  float4 r0 = *reinterpret_cast<const float4*>(rp);
  float4 r1 = *reinterpret_cast<const float4*>(rp + 4);
  f16x8 o;
  o[0] = (f16)(__expf((float)s[0] - m0.x) * r0.x);
  o[1] = (f16)(__expf((float)s[1] - m0.y) * r0.y);
  o[2] = (f16)(__expf((float)s[2] - m0.z) * r0.z);
  o[3] = (f16)(__expf((float)s[3] - m0.w) * r0.w);
  o[4] = (f16)(__expf((float)s[4] - m1.x) * r1.x);
  o[5] = (f16)(__expf((float)s[5] - m1.y) * r1.y);
  o[6] = (f16)(__expf((float)s[6] - m1.z) * r1.z);
  o[7] = (f16)(__expf((float)s[7] - m1.w) * r1.w);
  reinterpret_cast<f16x8*>(A)[i8] = o;
}

// ---------------- launch ----------------
extern "C" void kernel_launch(void* const* d_in, const int* in_sizes, int n_in,
                              void* d_out, int out_size, void* d_ws, size_t ws_size,
                              hipStream_t stream) {
  (void)in_sizes; (void)n_in; (void)out_size;
  const float* X = (const float*)d_in[0];      // [8,2048,2048]
  const float* W = (const float*)d_in[1];      // [2048,2048]
  const float* bias = (const float*)d_in[2];   // [2048]
  const float* gamma = (const float*)d_in[3];  // scalar

  char* ws = (char*)d_ws;
  f16* Xh = (f16*)(ws);                      // 67,108,864 B
  f16* Wh = (f16*)(ws + 67108864L);          //  8,388,608 B
  f16* Qh = (f16*)(ws + 75497472L);          // 67,108,864 B
  f16* Sh = (f16*)(ws + 142606336L);         // 67,108,864 B (f16 scores)
  float* Mp = (float*)(ws + 276824064L);     //    524,288 B
  float* Sp = (float*)(ws + 277348352L);     //    524,288 B
  float* Mx = (float*)(ws + 277872640L);     //     65,536 B
  float* Rs = (float*)(ws + 277938176L);     //     65,536 B
  f16* Amat = Qh;  // overlay: Q dead after GEMM2 (stream-ordered)
  if (ws_size < 278003712UL) return;

  cvt_f16<<<2048, 256, 0, stream>>>(X, Xh, 8388608L);
  cvt_f16<<<2048, 256, 0, stream>>>(W, Wh, 1048576L);

  dim3 gg(8, 8, 8), bb(512);
  // Q[b,n,f] = sum_e X[b,n,e] W[f,e] + bias[f]  -> fp16
  gemm256<1><<<gg, bb, 0, stream>>>(Xh, NNL, Wh, 0L, bias, nullptr, nullptr, Qh,
                                    nullptr, nullptr);
  // S[b,n,m] = sum_e Q[b,n,e] X[b,m,e] + gamma -> f16 Sh, + column stats
  gemm256<2><<<gg, bb, 0, stream>>>(Qh, NNL, Xh, NNL, nullptr, gamma, nullptr, Sh,
                                    Mp, Sp);
  stats_combine<<<dim3(8, 8), 256, 0, stream>>>(Mp, Sp, Mx, Rs);
  scale_exp_kernel<<<16384, 256, 0, stream>>>(Sh, Mx, Rs, Amat);
  // out[b,n,m] = sum_e X[b,n,e] attn[b,m,e]  -> fp32 d_out
  gemm256<0><<<gg, bb, 0, stream>>>(Xh, NNL, Amat, NNL, nullptr, nullptr,
                                    (float*)d_out, nullptr, nullptr, nullptr);
}

// Round 8
// 625.403 us; speedup vs baseline: 1.0141x; 1.0141x over previous
//
#include <hip/hip_runtime.h>
#include <stdint.h>

// B=8, N=E=2048.  All-fp16 single-product pipeline:
//  1) Xh = fp16(X), Wh = fp16(W)
//  2) Q = Xh·Wh^T + b   -> fp16 Qh
//  3) S = Qh·Xh^T + gamma -> fp16 Sh (+ fused column-softmax partial stats)
//  4) stats combine (8 partials -> Mx, Rs)
//  5) attn[b,m,e] = exp(Sh-M)*R -> fp16 (overlays Qh)
//  6) out = Xh·attn^T -> fp32
//
// R8 vs R7 (634 us; GEMM 138.6, MfmaUtil 44.8, R7 phase-prefetch NULL):
// 16 WAVES per block (1024 thr), same 256x256 tile / 128 KiB LDS / ledger.
// Rationale: per tile wall ~5200cy vs MFMA-pipe 2480 + LDS-pipe ~2800 --
// neither saturated, conflicts 0, read-latency ruled out (R7 null) => TLP
// bound at 2 waves/SIMD.  16 waves = 4/SIMD.  Wave grid 4Mx4N, per-wave
// 64x64 (acc[4][4]=64 VGPR; total ~120 <= 128 = 16-wave budget, m69).
//
// Schedule: 2 phases/tile {P0: rd kh0 frags (8 ds_read), STG A+B(e,k1,t+1),
// 16 MFMA} SYNC(4) {P1: rd kh1, STG A+B(d,k0,t+2), 16 MFMA} SYNC(4).
// Ledger (1 load per STG with 1024 thr; simulated):
//   prologue: stage t0.k0(2),t0.k1(2),t1.k0(2)=6; vmcnt(4) drains t0.k0;
//     out {t0.k1,t1.k0}=4
//   P0(t): +t+1.k1 -> 6; SYNC1 vmcnt(4) drains t.k1 (read at P1(t)) ✓
//   P1(t): +t+2.k0 -> 6; SYNC2 vmcnt(4) drains t+1.k0 (read P0(t+1)) ✓
//   tails: P1(NT-2) no stage -> SYNC2 vmcnt(2) drains (NT-1).k0;
//          SYNC1(NT-1) vmcnt(0) drains (NT-1).k1.
// W-after-R: P1's STG(d,k0) overwrites P0-read region -- issued after
// SYNC1's lgkmcnt(0)+barrier ✓; P0's STG(e,k1) overwrites P1(t-1)-read
// region -- after SYNC2(t-1) ✓.  Same hazard structure as R6 (2x
// post-timing-verified).  Per-element K order unchanged (kh0 then kh1 per
// tile) -> bit-identical: absmax MUST be exactly 0.1679688 or revert.
//
// XCD swizzle (R6, confirmed FETCH 270->98 MB) and LDS seg-XOR swizzle
// (0 conflicts) unchanged.  cvt reverted to R6 one-shot grids (R7 regressed).

typedef _Float16 f16;
typedef f16 f16x8 __attribute__((ext_vector_type(8)));
typedef f16 f16x4 __attribute__((ext_vector_type(4)));
typedef float f32x4 __attribute__((ext_vector_type(4)));

#define ND 2048
#define NNL 4194304L  // ND*ND
#define NT 32         // K tiles of 64

static __device__ __forceinline__ void stage16(const void* g, void* l) {
  __builtin_amdgcn_global_load_lds(
      (const __attribute__((address_space(1))) uint32_t*)g,
      (__attribute__((address_space(3))) uint32_t*)l, 16, 0, 0);
}

// ---------------- fp32 -> fp16 convert ----------------
__global__ void cvt_f16(const float* __restrict__ x, f16* __restrict__ h, int n4) {
  int i = blockIdx.x * 256 + threadIdx.x;
  if (i >= n4) return;
  float4 v = reinterpret_cast<const float4*>(x)[i];
  f16x4 o;
  o.x = (f16)v.x; o.y = (f16)v.y; o.z = (f16)v.z; o.w = (f16)v.w;
  reinterpret_cast<f16x4*>(h)[i] = o;
}

// region byte base within smem: d=dbuf(0/1), o=op(0=A,1=B), kh=K-half(0/1)
#define RB(d_, o_, kh_) ((((d_) << 2) | ((o_) << 1) | (kh_)) * 16384)

// stage one 16 KiB half-region (256 rows x 32 f16): ONE load round (1024 thr)
#define STG(gp_, ro_, t_, kh_) \
  stage16((gp_) + (long)(t_) * 128 + (kh_) * 64, smem + (ro_) + ld0)

#define FENCE asm volatile("" ::: "memory")

#define SYNC(vm_)                                                        \
  do {                                                                   \
    asm volatile("s_waitcnt vmcnt(" #vm_ ") lgkmcnt(0)" ::: "memory");   \
    __builtin_amdgcn_s_barrier();                                        \
    FENCE;                                                               \
  } while (0)

// One phase: read 4 A-frags + 4 B-frags for (d,kh), stage, 16 MFMAs.
// acc[mt][nt] += af[mt] x bf[nt]; per-element K order = kh0 then kh1 = R6.
#define PHASE(d_, kh_, STAGE_)                                                \
  do {                                                                        \
    const char* ra_ = smem + RB(d_, 0, kh_) + aoff;                           \
    const char* rb_ = smem + RB(d_, 1, kh_) + boff;                           \
    f16x8 af[4], bf[4];                                                       \
    _Pragma("unroll") for (int i_ = 0; i_ < 4; ++i_) {                        \
      af[i_] = *(const f16x8*)(ra_ + i_ * 1024);                              \
      bf[i_] = *(const f16x8*)(rb_ + i_ * 1024);                              \
    }                                                                         \
    STAGE_                                                                    \
    __builtin_amdgcn_s_setprio(1);                                            \
    _Pragma("unroll") for (int mt_ = 0; mt_ < 4; ++mt_) {                     \
      _Pragma("unroll") for (int nt_ = 0; nt_ < 4; ++nt_) {                   \
        acc[mt_][nt_] = __builtin_amdgcn_mfma_f32_16x16x32_f16(               \
            af[mt_], bf[nt_], acc[mt_][nt_], 0, 0, 0);                        \
      }                                                                       \
    }                                                                         \
    __builtin_amdgcn_s_setprio(0);                                            \
  } while (0)

// ---------------- GEMM: C[i,j] = dot(A[i,:], B[j,:])  (row-major, K=2048)
// MODE 1: + bias[j], fp16 store (Ch)
// MODE 0: fp32 store (Cf)
// MODE 2: + gamma, f16 store (Ch) + fused column-softmax partials -> Mp/Sp
template <int MODE>
__launch_bounds__(1024) __global__
void gemm256(const f16* __restrict__ A, long sA, const f16* __restrict__ B, long sB,
             const float* __restrict__ bias, const float* __restrict__ gamma,
             float* __restrict__ Cf, f16* __restrict__ Ch,
             float* __restrict__ Mp, float* __restrict__ Sp) {
  __shared__ char smem[131072];

  const int bz = blockIdx.z;
  // XCD-aware remap: xcd = blockIdx.x (= dispatch-linear % 8, x-fastest).
  const int bx = ((blockIdx.x & 1) << 2) | (blockIdx.y & 3);          // tn idx
  const int by = (((blockIdx.x >> 1) & 3) << 1) | (blockIdx.y >> 2);  // tm idx
  const long tm = (long)by * 256;
  const long tn = (long)bx * 256;
  const int tid = threadIdx.x;
  const int lane = tid & 63;
  const int wid = tid >> 6;          // 0..15
  const int wm = (wid >> 2) << 6;    // 0/64/128/192
  const int wn = (wid & 3) << 6;     // 0/64/128/192

  // staging: idx16 = tid -> row = tid>>2, s_lds = tid&3,
  // fetch global seg s_g = s_lds ^ ((row>>1)&3) = (tid&3)^((tid>>3)&3)
  const int sg = (tid & 3) ^ ((tid >> 3) & 3);
  const char* gA = (const char*)(A + bz * sA + tm * ND) + (long)(tid >> 2) * 4096 + sg * 16;
  const char* gB = (const char*)(B + bz * sB + tn * ND) + (long)(tid >> 2) * 4096 + sg * 16;
  const uint32_t ld0 = tid * 16u;

  // 16x16x32 frag reader (0 conflicts): LDS seg = (lane>>4) ^ ((row>>1)&3)
  const int segsw = (((lane >> 4) ^ ((lane >> 1) & 3)) << 4);  // bytes
  const int lrow = lane & 15;
  const int aoff = (wm + lrow) * 64 + segsw;
  const int boff = (wn + lrow) * 64 + segsw;

  f32x4 acc[4][4] = {};

  // prologue: t0.k0, t0.k1, t1.k0 (6 loads); vmcnt(4) drains t0.k0,
  // leaving {t0.k1, t1.k0} = 4 in flight = steady state.
  STG(gA, RB(0, 0, 0), 0, 0);
  STG(gB, RB(0, 1, 0), 0, 0);
  STG(gA, RB(0, 0, 1), 0, 1);
  STG(gB, RB(0, 1, 1), 0, 1);
  STG(gA, RB(1, 0, 0), 1, 0);
  STG(gB, RB(1, 1, 0), 1, 0);
  asm volatile("s_waitcnt vmcnt(4)" ::: "memory");
  __builtin_amdgcn_s_barrier();
  FENCE;

#pragma unroll 2
  for (int t = 0; t < NT - 2; ++t) {
    const int d = t & 1;
    const int e = d ^ 1;
    PHASE(d, 0, STG(gA, RB(e, 0, 1), t + 1, 1); STG(gB, RB(e, 1, 1), t + 1, 1););
    SYNC(4);  // drains t.k1 -> valid for P1
    PHASE(d, 1, STG(gA, RB(d, 0, 0), t + 2, 0); STG(gB, RB(d, 1, 0), t + 2, 0););
    SYNC(4);  // drains t+1.k0 -> valid for next P0
  }
  {  // t = NT-2 (even => d=0, e=1)
    PHASE(0, 0, STG(gA, RB(1, 0, 1), NT - 1, 1); STG(gB, RB(1, 1, 1), NT - 1, 1););
    SYNC(4);  // drains (NT-2).k1
    PHASE(0, 1, ;);
    SYNC(2);  // out {(NT-1).k0,(NT-1).k1}=4 -> drains (NT-1).k0
  }
  {  // t = NT-1 (odd => d=1)
    PHASE(1, 0, ;);
    SYNC(0);  // drains (NT-1).k1
    PHASE(1, 1, ;);
    // no sync: epilogue syncs itself where needed
  }

  // epilogue: C/D layout col=lane&15, row=(lane>>4)*4+reg  [verified m89/m91]
  const int rr = (lane >> 4) << 2;
  const int cc = lane & 15;
  const long cb = (long)bz * NNL;
  if constexpr (MODE == 1) {
#pragma unroll
    for (int nt = 0; nt < 4; ++nt) {
      const long col = tn + wn + nt * 16 + cc;
      const float bj = bias[col];
#pragma unroll
      for (int mt = 0; mt < 4; ++mt) {
#pragma unroll
        for (int r = 0; r < 4; ++r) {
          const long row = tm + wm + mt * 16 + rr + r;
          Ch[cb + row * ND + col] = (f16)(acc[mt][nt][r] + bj);
        }
      }
    }
  } else if constexpr (MODE == 0) {
#pragma unroll
    for (int mt = 0; mt < 4; ++mt) {
#pragma unroll
      for (int nt = 0; nt < 4; ++nt) {
#pragma unroll
        for (int r = 0; r < 4; ++r) {
          const long row = tm + wm + mt * 16 + rr + r;
          const long col = tn + wn + nt * 16 + cc;
          Cf[cb + row * ND + col] = acc[mt][nt][r];
        }
      }
    }
  } else {  // MODE 2: f16 score store + fused column-softmax partials
    const float g = gamma[0];
    // round scores to f16 FIRST; stats from rounded values so that
    // attn = exact softmax(s16) (dominant-entry rounding cancels).
#pragma unroll
    for (int mt = 0; mt < 4; ++mt)
#pragma unroll
      for (int nt = 0; nt < 4; ++nt)
#pragma unroll
        for (int r = 0; r < 4; ++r)
          acc[mt][nt][r] = (float)(f16)(acc[mt][nt][r] + g);
    __syncthreads();  // all waves done with smem tiles -> safe to reuse
    float* redm = (float*)smem;  // [16 wid][4 nt][16 cc] = 1024 floats
    float* reds = redm + 1024;
#pragma unroll
    for (int nt = 0; nt < 4; ++nt) {
      // lane covers col cc (of nt), rows rr..rr+3 of 4 mt blocks (64 rows)
      float ml = -3.4e38f;
#pragma unroll
      for (int mt = 0; mt < 4; ++mt)
#pragma unroll
        for (int r = 0; r < 4; ++r)
          ml = fmaxf(ml, acc[mt][nt][r]);
      float sl = 0.f;
#pragma unroll
      for (int mt = 0; mt < 4; ++mt)
#pragma unroll
        for (int r = 0; r < 4; ++r)
          sl += __expf(acc[mt][nt][r] - ml);
      // butterfly over lane bits 4,5: combine the 4 rr-stripes of column cc
#pragma unroll
      for (int off = 16; off < 64; off <<= 1) {
        float pm = __shfl_xor(ml, off, 64);
        float ps = __shfl_xor(sl, off, 64);
        float nm = fmaxf(ml, pm);
        sl = sl * __expf(ml - nm) + ps * __expf(pm - nm);
        ml = nm;
      }
      if ((lane >> 4) == 0) {
        redm[wid * 64 + nt * 16 + lrow] = ml;
        reds[wid * 64 + nt * 16 + lrow] = sl;
      }
    }
    __syncthreads();
    if (tid < 256) {
      // col index c = tid; contributions from wid = (c>>6) + 4k, k=0..3
      const int wbase = (tid >> 6);          // wn group
      const int ntc = (tid >> 4) & 3;
      const int ccc = tid & 15;
      float m = -3.4e38f, s = 0.f;
#pragma unroll
      for (int k = 0; k < 4; ++k) {
        const int w = wbase + 4 * k;
        const float mk = redm[w * 64 + ntc * 16 + ccc];
        const float sk = reds[w * 64 + ntc * 16 + ccc];
        const float nm = fmaxf(m, mk);
        s = s * __expf(m - nm) + sk * __expf(mk - nm);
        m = nm;
      }
      const long o = ((long)bz * 8 + by) * ND + tn + tid;
      Mp[o] = m;
      Sp[o] = s;
    }
    // S store (f16; acc already rounded so this conversion is exact)
#pragma unroll
    for (int mt = 0; mt < 4; ++mt) {
#pragma unroll
      for (int nt = 0; nt < 4; ++nt) {
#pragma unroll
        for (int r = 0; r < 4; ++r) {
          const long row = tm + wm + mt * 16 + rr + r;
          const long col = tn + wn + nt * 16 + cc;
          Ch[cb + row * ND + col] = (f16)acc[mt][nt][r];
        }
      }
    }
  }
}

// ---------------- stats combine (8 n-segment partials -> Mx, 1/sum) --------
__global__ void stats_combine(const float* __restrict__ Mp, const float* __restrict__ Sp,
                              float* __restrict__ Mx, float* __restrict__ Rs) {
  const int col = blockIdx.x * 256 + threadIdx.x;
  const int b = blockIdx.y;
  float m = -3.4e38f, s = 0.f;
  for (int k = 0; k < 8; ++k) {
    const long o = ((long)b * 8 + k) * ND + col;
    float mk = Mp[o], sk = Sp[o];
    float nm = fmaxf(m, mk);
    s = s * __expf(m - nm) + sk * __expf(mk - nm);
    m = nm;
  }
  Mx[(long)b * ND + col] = m;
  Rs[(long)b * ND + col] = 1.0f / s;
}

// attn[b,m,e] = exp(Sh[b,m,e] - Mx[b,e]) * Rs[b,e]  -> fp16, same layout as Sh
__global__ void scale_exp_kernel(const f16* __restrict__ S, const float* __restrict__ Mx,
                                 const float* __restrict__ Rs, f16* __restrict__ A) {
  const long i8 = (long)blockIdx.x * 256 + threadIdx.x;  // total/8
  const long i = i8 * 8;
  const int b = (int)(i >> 22);     // N*N = 2^22
  const int col = (int)(i & 2047);  // e index (multiple of 8)
  f16x8 s = reinterpret_cast<const f16x8*>(S)[i8];
  const float* mp = &Mx[(long)b * ND + col];
  const float* rp = &Rs[(long)b * ND + col];
  float4 m0 = *reinterpret_cast<const float4*>(mp);
  float4 m1 = *reinterpret_cast<const float4*>(mp + 4);
  float4 r0 = *reinterpret_cast<const float4*>(rp);
  float4 r1 = *reinterpret_cast<const float4*>(rp + 4);
  f16x8 o;
  o[0] = (f16)(__expf((float)s[0] - m0.x) * r0.x);
  o[1] = (f16)(__expf((float)s[1] - m0.y) * r0.y);
  o[2] = (f16)(__expf((float)s[2] - m0.z) * r0.z);
  o[3] = (f16)(__expf((float)s[3] - m0.w) * r0.w);
  o[4] = (f16)(__expf((float)s[4] - m1.x) * r1.x);
  o[5] = (f16)(__expf((float)s[5] - m1.y) * r1.y);
  o[6] = (f16)(__expf((float)s[6] - m1.z) * r1.z);
  o[7] = (f16)(__expf((float)s[7] - m1.w) * r1.w);
  reinterpret_cast<f16x8*>(A)[i8] = o;
}

// ---------------- launch ----------------
extern "C" void kernel_launch(void* const* d_in, const int* in_sizes, int n_in,
                              void* d_out, int out_size, void* d_ws, size_t ws_size,
                              hipStream_t stream) {
  (void)in_sizes; (void)n_in; (void)out_size;
  const float* X = (const float*)d_in[0];      // [8,2048,2048]
  const float* W = (const float*)d_in[1];      // [2048,2048]
  const float* bias = (const float*)d_in[2];   // [2048]
  const float* gamma = (const float*)d_in[3];  // scalar

  char* ws = (char*)d_ws;
  f16* Xh = (f16*)(ws);                      // 67,108,864 B
  f16* Wh = (f16*)(ws + 67108864L);          //  8,388,608 B
  f16* Qh = (f16*)(ws + 75497472L);          // 67,108,864 B
  f16* Sh = (f16*)(ws + 142606336L);         // 67,108,864 B (f16 scores)
  float* Mp = (float*)(ws + 276824064L);     //    524,288 B
  float* Sp = (float*)(ws + 277348352L);     //    524,288 B
  float* Mx = (float*)(ws + 277872640L);     //     65,536 B
  float* Rs = (float*)(ws + 277938176L);     //     65,536 B
  f16* Amat = Qh;  // overlay: Q dead after GEMM2 (stream-ordered)
  if (ws_size < 278003712UL) return;

  cvt_f16<<<32768, 256, 0, stream>>>(X, Xh, 8388608);
  cvt_f16<<<4096, 256, 0, stream>>>(W, Wh, 1048576);

  dim3 gg(8, 8, 8), bb(1024);
  // Q[b,n,f] = sum_e X[b,n,e] W[f,e] + bias[f]  -> fp16
  gemm256<1><<<gg, bb, 0, stream>>>(Xh, NNL, Wh, 0L, bias, nullptr, nullptr, Qh,
                                    nullptr, nullptr);
  // S[b,n,m] = sum_e Q[b,n,e] X[b,m,e] + gamma -> f16 Sh, + column stats
  gemm256<2><<<gg, bb, 0, stream>>>(Qh, NNL, Xh, NNL, nullptr, gamma, nullptr, Sh,
                                    Mp, Sp);
  stats_combine<<<dim3(8, 8), 256, 0, stream>>>(Mp, Sp, Mx, Rs);
  scale_exp_kernel<<<16384, 256, 0, stream>>>(Sh, Mx, Rs, Amat);
  // out[b,n,m] = sum_e X[b,n,e] attn[b,m,e]  -> fp32 d_out
  gemm256<0><<<gg, bb, 0, stream>>>(Xh, NNL, Amat, NNL, nullptr, nullptr,
                                    (float*)d_out, nullptr, nullptr, nullptr);
}